// Round 20
// baseline (192.881 us; speedup 1.0000x reference)
//
#include <hip/hip_runtime.h>

#define DD 4096
#define NROWS 16384
#define EPS 1e-6f

typedef float fx4 __attribute__((ext_vector_type(4)));
typedef int   ix4 __attribute__((ext_vector_type(4)));

// ws: +0 float gmax, +256 float rowmax[16384].
// q8 intermediate in d_out (r14 layout, proven): row r dwords
// [4096r, 4096r+1024); dword 4t+i <-> fx4 slot t+256i.

// Pass 1 with CHANNEL-DESYNC: res is loaded with a +512B-rotated wave
// footprint (slot (t+32)&255 within each 4KB chunk) into linear LDS, so
// res wave-instructions never share an HBM channel phase with x's.
// x goes straight to registers at the aligned footprint. One barrier,
// then compute y = x_reg + res_lds elementwise (slots realigned via LDS).
__global__ __launch_bounds__(256) void pass1_rot(
    const float* __restrict__ x, const float* __restrict__ res,
    const float* __restrict__ gamma, unsigned int* __restrict__ outw,
    float* __restrict__ rowmax) {
  __shared__ float rl[DD];            // 16 KB: res row, linear
  __shared__ float s_ss[4], s_mx[4];

  const int row = blockIdx.x;
  const int t = threadIdx.x;
  const fx4* x4 = (const fx4*)(x + (size_t)row * DD);
  const fx4* r4 = (const fx4*)(res + (size_t)row * DD);
  const fx4* g4 = (const fx4*)gamma;
  fx4* rl4 = (fx4*)rl;

  // rotated res stage: footprint of each wave-instr shifted +32 fx4 (512B)
  fx4 xv[4];
#pragma unroll
  for (int i = 0; i < 4; ++i) {
    const int s = i * 256 + ((t + 32) & 255);  // bijective per 4KB chunk
    rl4[s] = r4[s];          // global slot s -> LDS slot s (linear)
    xv[i] = x4[t + i * 256]; // aligned footprint, kept in regs
  }
  __syncthreads();

  fx4 p[4];
  float ss = 0.f, mx = 0.f;
#pragma unroll
  for (int i = 0; i < 4; ++i) {
    const int idx = t + i * 256;
    fx4 y = xv[i] + rl4[idx];
    ss += y.x * y.x + y.y * y.y + y.z * y.z + y.w * y.w;
    p[i] = y * g4[idx];
    mx = fmaxf(mx, fmaxf(fmaxf(fabsf(p[i].x), fabsf(p[i].y)),
                         fmaxf(fabsf(p[i].z), fabsf(p[i].w))));
  }
#pragma unroll
  for (int off = 32; off > 0; off >>= 1) {
    ss += __shfl_down(ss, off, 64);
    mx = fmaxf(mx, __shfl_down(mx, off, 64));
  }
  const int wave = t >> 6, lane = t & 63;
  if (lane == 0) { s_ss[wave] = ss; s_mx[wave] = mx; }
  __syncthreads();
  const float tss = s_ss[0] + s_ss[1] + s_ss[2] + s_ss[3];
  const float tmx = fmaxf(fmaxf(s_mx[0], s_mx[1]), fmaxf(s_mx[2], s_mx[3]));
  const float rs = rsqrtf(tss * (1.0f / DD) + EPS);
  if (t == 0) rowmax[row] = tmx * rs;          // normalized row max
  const float inv = tmx > 0.f ? 127.0f / tmx : 0.f;

  ix4 d;
  int* dp = (int*)&d;
#pragma unroll
  for (int i = 0; i < 4; ++i) {
    int a = min(max(__float2int_rn(p[i].x * inv), -127), 127);
    int b = min(max(__float2int_rn(p[i].y * inv), -127), 127);
    int c = min(max(__float2int_rn(p[i].z * inv), -127), 127);
    int e = min(max(__float2int_rn(p[i].w * inv), -127), 127);
    dp[i] = (a & 255) | ((b & 255) << 8) | ((c & 255) << 16) | ((e & 255) << 24);
  }
  *(ix4*)(outw + (size_t)row * DD + 4 * t) = d;  // coalesced q8 store
}

__global__ __launch_bounds__(1024) void reduce_gmax(
    const float* __restrict__ rowmax, float* __restrict__ gmax) {
  const int t = threadIdx.x;
  float m = 0.f;
#pragma unroll
  for (int i = 0; i < NROWS / 1024; ++i) m = fmaxf(m, rowmax[t + i * 1024]);
#pragma unroll
  for (int off = 32; off > 0; off >>= 1) m = fmaxf(m, __shfl_down(m, off, 64));
  __shared__ float s[16];
  if ((t & 63) == 0) s[t >> 6] = m;
  __syncthreads();
  if (t == 0) {
    float r = s[0];
#pragma unroll
    for (int i = 1; i < 16; ++i) r = fmaxf(r, s[i]);
    *gmax = r;
  }
}

// Pass 2 (r14's, proven): thread t reads its own ix4 at dword 4t, rescales
// by rowmax/gmax, overwrites its row span (per-thread RAW only -> race-free).
__global__ __launch_bounds__(256) void pass2(
    unsigned int* __restrict__ outw, const float* __restrict__ rowmax,
    const float* __restrict__ gmax, int* __restrict__ out) {
  const int row = blockIdx.x;
  const int t = threadIdx.x;
  const float c = rowmax[row] / *gmax;  // <= 1
  union { ix4 v; unsigned int w[4]; } u;
  u.v = *(const ix4*)(outw + (size_t)row * DD + 4 * t);
  ix4* orow = (ix4*)(out + (size_t)row * DD);
#pragma unroll
  for (int i = 0; i < 4; ++i) {
    const unsigned int w = u.w[i];
    ix4 q;
    q.x = min(max(__float2int_rn((float)((int)(w << 24) >> 24) * c), -128), 127);
    q.y = min(max(__float2int_rn((float)((int)(w << 16) >> 24) * c), -128), 127);
    q.z = min(max(__float2int_rn((float)((int)(w << 8) >> 24) * c), -128), 127);
    q.w = min(max(__float2int_rn((float)((int)w >> 24) * c), -128), 127);
    orow[t + i * 256] = q;  // i=0 exactly covers the dwords read
  }
}

// ---- Fallback (ws < 1 MB): recompute path ----
__global__ __launch_bounds__(256) void pass1_nb(
    const float* __restrict__ x, const float* __restrict__ res,
    const float* __restrict__ gamma, float* __restrict__ rstd,
    float* __restrict__ rowmax) {
  const int row = blockIdx.x;
  const int t = threadIdx.x;
  const fx4* x4 = (const fx4*)(x + (size_t)row * DD);
  const fx4* r4 = (const fx4*)(res + (size_t)row * DD);
  const fx4* g4 = (const fx4*)gamma;
  float ss = 0.f, mx = 0.f;
#pragma unroll
  for (int i = 0; i < 4; ++i) {
    const int idx = t + i * 256;
    fx4 y = x4[idx] + r4[idx];
    ss += y.x * y.x + y.y * y.y + y.z * y.z + y.w * y.w;
    fx4 p = y * g4[idx];
    mx = fmaxf(mx, fmaxf(fmaxf(fabsf(p.x), fabsf(p.y)),
                         fmaxf(fabsf(p.z), fabsf(p.w))));
  }
#pragma unroll
  for (int off = 32; off > 0; off >>= 1) {
    ss += __shfl_down(ss, off, 64);
    mx = fmaxf(mx, __shfl_down(mx, off, 64));
  }
  __shared__ float s_ss[4], s_mx[4];
  const int wave = t >> 6, lane = t & 63;
  if (lane == 0) { s_ss[wave] = ss; s_mx[wave] = mx; }
  __syncthreads();
  if (t == 0) {
    float tss = s_ss[0] + s_ss[1] + s_ss[2] + s_ss[3];
    float tmx = fmaxf(fmaxf(s_mx[0], s_mx[1]), fmaxf(s_mx[2], s_mx[3]));
    float rs = rsqrtf(tss * (1.0f / DD) + EPS);
    rstd[row] = rs;
    rowmax[row] = tmx * rs;
  }
}

__global__ __launch_bounds__(256) void pass2_nb(
    const float* __restrict__ x, const float* __restrict__ res,
    const float* __restrict__ gamma, const float* __restrict__ rstd,
    const float* __restrict__ gmax, int* __restrict__ out) {
  const int row = blockIdx.x;
  const int t = threadIdx.x;
  const float c = rstd[row] * (127.0f / *gmax);
  const fx4* x4 = (const fx4*)(x + (size_t)row * DD);
  const fx4* r4 = (const fx4*)(res + (size_t)row * DD);
  const fx4* g4 = (const fx4*)gamma;
  ix4* o4 = (ix4*)(out + (size_t)row * DD);
#pragma unroll
  for (int i = 0; i < 4; ++i) {
    const int idx = t + i * 256;
    fx4 xv = x4[idx], rv = r4[idx], gv = g4[idx];
    ix4 q;
    q.x = min(max(__float2int_rn((xv.x + rv.x) * gv.x * c), -128), 127);
    q.y = min(max(__float2int_rn((xv.y + rv.y) * gv.y * c), -128), 127);
    q.z = min(max(__float2int_rn((xv.z + rv.z) * gv.z * c), -128), 127);
    q.w = min(max(__float2int_rn((xv.w + rv.w) * gv.w * c), -128), 127);
    o4[idx] = q;
  }
}

extern "C" void kernel_launch(void* const* d_in, const int* in_sizes, int n_in,
                              void* d_out, int out_size, void* d_ws, size_t ws_size,
                              hipStream_t stream) {
  const float* x     = (const float*)d_in[0];
  const float* res   = (const float*)d_in[1];
  const float* gamma = (const float*)d_in[2];
  int* out = (int*)d_out;

  char* ws = (char*)d_ws;
  float* gmax   = (float*)ws;
  float* rowmax = (float*)(ws + 256);
  float* rstd   = (float*)(ws + 256 + 64 * 1024);  // fallback only

  if (ws_size >= (size_t)(1 << 20)) {
    unsigned int* outw = (unsigned int*)d_out;
    pass1_rot<<<NROWS, 256, 0, stream>>>(x, res, gamma, outw, rowmax);
    reduce_gmax<<<1, 1024, 0, stream>>>(rowmax, gmax);
    pass2<<<NROWS, 256, 0, stream>>>(outw, rowmax, gmax, out);
  } else {
    pass1_nb<<<NROWS, 256, 0, stream>>>(x, res, gamma, rstd, rowmax);
    reduce_gmax<<<1, 1024, 0, stream>>>(rowmax, gmax);
    pass2_nb<<<NROWS, 256, 0, stream>>>(x, res, gamma, rstd, gmax, out);
  }
}